// Round 17
// baseline (349.271 us; speedup 1.0000x reference)
//
#include <hip/hip_runtime.h>
#include <cstdint>
#include <cstddef>

#define NEG_SLOPE 0.2f

typedef _Float16 f16x8 __attribute__((ext_vector_type(8)));
typedef _Float16 f16x2 __attribute__((ext_vector_type(2)));
typedef float    f32x4 __attribute__((ext_vector_type(4)));
typedef float    f32x2 __attribute__((ext_vector_type(2)));

__device__ __forceinline__ float leaky(float x){ return x > 0.f ? x : NEG_SLOPE * x; }
__device__ __forceinline__ float elu(float x){ return x > 0.f ? x : __expf(x) - 1.f; }

// ============ prep: W1/W2 -> split fp16 hi/lo, + fold attention vectors through W1 ============
__global__ __launch_bounds__(256) void k_prep(const float* __restrict__ W1,
                                              const float* __restrict__ W2,
                                              const float* __restrict__ as1,
                                              const float* __restrict__ ad1,
                                              _Float16* __restrict__ W1hi, _Float16* __restrict__ W1lo,
                                              _Float16* __restrict__ W2hi, _Float16* __restrict__ W2lo,
                                              float* __restrict__ w_s, float* __restrict__ w_d)
{
    int b = blockIdx.x;
    if (b < 512) {
        const float* src = (b < 256) ? W1 : W2;
        _Float16* hi = (b < 256) ? W1hi : W2hi;
        _Float16* lo = (b < 256) ? W1lo : W2lo;
        int i = ((b & 255) << 8) + threadIdx.x;
        float v = src[i];
        _Float16 h = (_Float16)v;
        hi[i] = h;
        lo[i] = (_Float16)(v - (float)h);
    } else {
        int h = (b - 512) * 2 + (threadIdx.x >> 7);
        int k = threadIdx.x & 127;
        float s = 0.f, d = 0.f;
        for (int c = 0; c < 128; ++c) {
            float w = W1[((size_t)(h * 128 + c)) * 128 + k];
            s += as1[h * 128 + c] * w;
            d += ad1[h * 128 + c] * w;
        }
        w_s[h * 128 + k] = s;
        w_d[h * 128 + k] = d;
    }
}

// ============ fp16-A x split-fp16-B MFMA GEMM (tile 128x128, BK=32, z = heads) ============
#define LSG 40    // halfs per staging row (32 + 8 pad)
#define CP  136   // halfs per C-tile row (128 + 8 pad)
template<bool FUSE_BIAS_ELU, bool FUSE_ATTN2>
__global__ __launch_bounds__(256, 2) void k_gemm_h(
    const _Float16* __restrict__ A, const _Float16* __restrict__ Bh,
    const _Float16* __restrict__ Bl, const float* __restrict__ bias,
    _Float16* __restrict__ C,
    const float* __restrict__ as2, const float* __restrict__ ad2,
    float* __restrict__ As2, float* __restrict__ Ad2,
    int M, int K, int lda, int ldb, int ldc,
    long aZ, long bZ, long cZ, long biasZ)
{
    __shared__ __align__(16) _Float16 smem[128 * CP];
    _Float16* As  = smem;
    _Float16* Bhs = smem + 128 * LSG;
    _Float16* Bls = smem + 256 * LSG;

    const _Float16* Ab  = A  + (size_t)blockIdx.z * aZ;
    const _Float16* Bhb = Bh + (size_t)blockIdx.z * bZ;
    const _Float16* Blb = Bl + (size_t)blockIdx.z * bZ;
    _Float16* Cb = C + (size_t)blockIdx.z * cZ;

    const int tid = threadIdx.x;
    const int wave = tid >> 6, lane = tid & 63;
    const int wm = wave >> 1, wn = wave & 1;
    const int quad = lane >> 4, l16 = lane & 15;
    const int m0 = blockIdx.x * 128;

    f32x4 acc[4][4] = {};

    for (int k0 = 0; k0 < K; k0 += 32) {
        #pragma unroll
        for (int q = 0; q < 2; ++q) {
            int idx = tid + q * 256;
            int row = idx >> 2, kq = idx & 3;
            int rg = m0 + row;
            f16x8 va = {};
            if (rg < M) va = *(const f16x8*)(Ab + (size_t)rg * lda + k0 + kq * 8);
            *(f16x8*)&As[row * LSG + kq * 8] = va;
            *(f16x8*)&Bhs[row * LSG + kq * 8] = *(const f16x8*)(Bhb + (size_t)row * ldb + k0 + kq * 8);
            *(f16x8*)&Bls[row * LSG + kq * 8] = *(const f16x8*)(Blb + (size_t)row * ldb + k0 + kq * 8);
        }
        __syncthreads();

        f16x8 af[4], bhf[4], blf[4];
        #pragma unroll
        for (int i = 0; i < 4; ++i) {
            int mr = wm * 64 + i * 16 + l16;
            af[i] = *(const f16x8*)&As[mr * LSG + quad * 8];
            int nr = wn * 64 + i * 16 + l16;
            bhf[i] = *(const f16x8*)&Bhs[nr * LSG + quad * 8];
            blf[i] = *(const f16x8*)&Bls[nr * LSG + quad * 8];
        }
        #pragma unroll
        for (int i = 0; i < 4; ++i)
            #pragma unroll
            for (int j = 0; j < 4; ++j) {
                acc[i][j] = __builtin_amdgcn_mfma_f32_16x16x32_f16(af[i], bhf[j], acc[i][j], 0, 0, 0);
                acc[i][j] = __builtin_amdgcn_mfma_f32_16x16x32_f16(af[i], blf[j], acc[i][j], 0, 0, 0);
            }
        __syncthreads();
    }

    #pragma unroll
    for (int j = 0; j < 4; ++j) {
        int n = wn * 64 + j * 16 + l16;
        float bb = 0.f;
        if (FUSE_BIAS_ELU) bb = bias[blockIdx.z * biasZ + n];
        #pragma unroll
        for (int i = 0; i < 4; ++i)
            #pragma unroll
            for (int r = 0; r < 4; ++r) {
                float v = acc[i][j][r];
                if (FUSE_BIAS_ELU) v = elu(v + bb);
                smem[(wm * 64 + i * 16 + quad * 4 + r) * CP + n] = (_Float16)v;
            }
    }
    __syncthreads();
    for (int c = tid; c < 2048; c += 256) {
        int row = c >> 4, col8 = (c & 15) * 8;
        int m = m0 + row;
        if (m < M)
            *(f16x8*)(Cb + (size_t)m * ldc + col8) = *(const f16x8*)&smem[row * CP + col8];
    }
    if (FUSE_ATTN2) {
        int row = tid >> 1, half = tid & 1;
        int d = m0 + row;
        float ss = 0.f, sd = 0.f;
        const _Float16* rp = &smem[row * CP + half * 64];
        #pragma unroll
        for (int c8 = 0; c8 < 8; ++c8) {
            f16x8 v = *(const f16x8*)(rp + c8 * 8);
            #pragma unroll
            for (int c = 0; c < 8; ++c) {
                float f = (float)v[c];
                int n = half * 64 + c8 * 8 + c;
                ss += f * as2[n];
                sd += f * ad2[n];
            }
        }
        ss += __shfl_xor(ss, 1);
        sd += __shfl_xor(sd, 1);
        if (half == 0 && d < M) { As2[d] = ss; Ad2[d] = sd; }
    }
}

// ============ layer-1 attention logits from raw x; also emit x as fp16 ============
__global__ __launch_bounds__(256) void k_attn_x(const float* __restrict__ x,
                                                const float* __restrict__ w_s,
                                                const float* __restrict__ w_d,
                                                float* __restrict__ a_s,
                                                float* __restrict__ a_d,
                                                _Float16* __restrict__ xh, int N)
{
    int n = blockIdx.x * 4 + (threadIdx.x >> 6);
    if (n >= N) return;
    int lane = threadIdx.x & 63;
    float2 xv = *(const float2*)(x + (size_t)n * 128 + lane * 2);
    f16x2 hv = { (_Float16)xv.x, (_Float16)xv.y };
    *(f16x2*)(xh + (size_t)n * 128 + lane * 2) = hv;
    float ps[4], pd[4];
    #pragma unroll
    for (int h = 0; h < 4; ++h) {
        float2 sv = *(const float2*)(w_s + h * 128 + lane * 2);
        float2 dv = *(const float2*)(w_d + h * 128 + lane * 2);
        ps[h] = xv.x * sv.x + xv.y * sv.y;
        pd[h] = xv.x * dv.x + xv.y * dv.y;
    }
    #pragma unroll
    for (int h = 0; h < 4; ++h)
        for (int off = 32; off; off >>= 1) {
            ps[h] += __shfl_xor(ps[h], off);
            pd[h] += __shfl_xor(pd[h], off);
        }
    if (lane == 0) {
        *(float4*)(a_s + (size_t)n * 4) = make_float4(ps[0], ps[1], ps[2], ps[3]);
        *(float4*)(a_d + (size_t)n * 4) = make_float4(pd[0], pd[1], pd[2], pd[3]);
    }
}

// ============ CSR construction (count+rank, fused graph boundaries) ============
__global__ void k_count(const int* __restrict__ ei, int* __restrict__ deg,
                        unsigned short* __restrict__ rank,
                        const int* __restrict__ batch, int* __restrict__ gstart,
                        int E, int Ep, int N, int G, int nbc)
{
    if ((int)blockIdx.x < nbc) {
        int e = blockIdx.x * 256 + threadIdx.x;
        if (e >= Ep) return;
        int dst = (e < E) ? ei[E + e] : (e - E);
        rank[e] = (unsigned short)atomicAdd(&deg[dst], 1);
    } else {
        int n = (blockIdx.x - nbc) * 256 + threadIdx.x;
        if (n >= N) return;
        int b = batch[n];
        int prev = (n == 0) ? -1 : batch[n - 1];
        for (int g = prev + 1; g <= b; ++g) gstart[g] = n;
        if (n == N - 1)
            for (int g = b + 1; g <= G; ++g) gstart[g] = N;
    }
}

__global__ __launch_bounds__(1024) void k_scanA(const int* __restrict__ deg,
                                                int* __restrict__ start,
                                                int* __restrict__ sums, int Ntot, int N)
{
    __shared__ int sm[1024];
    int tid = threadIdx.x;
    int i = blockIdx.x * 1024 + tid;
    int v = (i < N) ? deg[i] : 0;
    sm[tid] = v; __syncthreads();
    for (int off = 1; off < 1024; off <<= 1) {
        int t = (tid >= off) ? sm[tid - off] : 0;
        __syncthreads();
        sm[tid] += t;
        __syncthreads();
    }
    if (i < Ntot) start[i] = sm[tid] - v;
    if (tid == 1023) sums[blockIdx.x] = sm[1023];
}

__global__ void k_scanB(int* sums, int nb)
{
    int l = threadIdx.x;
    int v = (l < nb) ? sums[l] : 0;
    int orig = v;
    for (int off = 1; off < 64; off <<= 1) { int t = __shfl_up(v, off); if (l >= off) v += t; }
    if (l < nb) sums[l] = v - orig;
}

__global__ __launch_bounds__(1024) void k_scanC(int* __restrict__ start,
                                                const int* __restrict__ sums, int Ntot)
{
    int i = blockIdx.x * 1024 + threadIdx.x;
    if (i < Ntot) start[i] += sums[blockIdx.x];
}

__global__ void k_fill(const int* __restrict__ ei, const int* __restrict__ start,
                       const unsigned short* __restrict__ rank,
                       unsigned short* __restrict__ csr_src, int E, int Ep)
{
    int e = blockIdx.x * blockDim.x + threadIdx.x;
    if (e >= Ep) return;
    int src, dst;
    if (e < E) { src = ei[e]; dst = ei[E + e]; } else { src = dst = e - E; }
    csr_src[start[dst] + rank[e]] = (unsigned short)src;
}

// ============ layer-1 gather: 16-lane group per dst (round-15 proven best: no unroll) ============
__global__ __launch_bounds__(256) void k_gat1(const int* __restrict__ start,
                                              const unsigned short* __restrict__ csr,
                                              const float* __restrict__ a_s,
                                              const float* __restrict__ a_d,
                                              const _Float16* __restrict__ x,
                                              _Float16* __restrict__ agg, int N)
{
    int d = blockIdx.x * 16 + (threadIdx.x >> 4);
    if (d >= N) return;
    int g16 = threadIdx.x & 15;
    int beg = start[d], end = start[d + 1];
    int deg = end - beg;
    float4 ad4 = *(const float4*)(a_d + (size_t)d * 4);

    float sum0 = 0.f, sum1 = 0.f, sum2 = 0.f, sum3 = 0.f;
    f32x2 acc[4][4] = {};
    const _Float16* xb = x + g16 * 8;

    for (int base = 0; base < deg; base += 16) {
        int nch = deg - base; if (nch > 16) nch = 16;
        int s = 0;
        float e0 = 0.f, e1 = 0.f, e2 = 0.f, e3 = 0.f;
        if (g16 < nch) {
            s = csr[beg + base + g16];
            float4 as4 = *(const float4*)(a_s + (size_t)s * 4);
            e0 = __expf(leaky(as4.x + ad4.x));
            e1 = __expf(leaky(as4.y + ad4.y));
            e2 = __expf(leaky(as4.z + ad4.z));
            e3 = __expf(leaky(as4.w + ad4.w));
            sum0 += e0; sum1 += e1; sum2 += e2; sum3 += e3;
        }
        for (int t = 0; t < nch; ++t) {
            int   si = __shfl(s,  t, 16);
            float w0 = __shfl(e0, t, 16);
            float w1 = __shfl(e1, t, 16);
            float w2 = __shfl(e2, t, 16);
            float w3 = __shfl(e3, t, 16);
            f16x8 hv = *(const f16x8*)(xb + (size_t)si * 128);
            f32x2 v0 = { (float)hv[0], (float)hv[1] };
            f32x2 v1 = { (float)hv[2], (float)hv[3] };
            f32x2 v2 = { (float)hv[4], (float)hv[5] };
            f32x2 v3 = { (float)hv[6], (float)hv[7] };
            acc[0][0] += w0 * v0; acc[0][1] += w0 * v1; acc[0][2] += w0 * v2; acc[0][3] += w0 * v3;
            acc[1][0] += w1 * v0; acc[1][1] += w1 * v1; acc[1][2] += w1 * v2; acc[1][3] += w1 * v3;
            acc[2][0] += w2 * v0; acc[2][1] += w2 * v1; acc[2][2] += w2 * v2; acc[2][3] += w2 * v3;
            acc[3][0] += w3 * v0; acc[3][1] += w3 * v1; acc[3][2] += w3 * v2; acc[3][3] += w3 * v3;
        }
    }
    #pragma unroll
    for (int o = 1; o < 16; o <<= 1) {
        sum0 += __shfl_xor(sum0, o, 16); sum1 += __shfl_xor(sum1, o, 16);
        sum2 += __shfl_xor(sum2, o, 16); sum3 += __shfl_xor(sum3, o, 16);
    }
    float inv[4] = { 1.f / (sum0 + 1e-16f), 1.f / (sum1 + 1e-16f),
                     1.f / (sum2 + 1e-16f), 1.f / (sum3 + 1e-16f) };
    _Float16* o = agg + (size_t)d * 512 + g16 * 8;
    #pragma unroll
    for (int h = 0; h < 4; ++h) {
        f16x8 ov;
        #pragma unroll
        for (int p = 0; p < 4; ++p) {
            ov[2 * p]     = (_Float16)(acc[h][p].x * inv[h]);
            ov[2 * p + 1] = (_Float16)(acc[h][p].y * inv[h]);
        }
        *(f16x8*)(o + h * 128) = ov;
    }
}

// ============ layer-2 gather + bias + ELU -> h2 fp16, 16-lane group, 4-edge unrolled ============
__global__ __launch_bounds__(256) void k_gat2(const int* __restrict__ start,
                                              const unsigned short* __restrict__ csr,
                                              const float* __restrict__ a_s,
                                              const float* __restrict__ a_d,
                                              const _Float16* __restrict__ xh2,
                                              const float* __restrict__ b2,
                                              _Float16* __restrict__ h2, int N)
{
    int d = blockIdx.x * 16 + (threadIdx.x >> 4);
    if (d >= N) return;
    int g16 = threadIdx.x & 15;
    int beg = start[d], end = start[d + 1];
    int deg = end - beg;
    float ad = a_d[d];

    float sum = 0.f;
    f32x2 acc[4] = {};
    const _Float16* xb = xh2 + g16 * 8;

    for (int base = 0; base < deg; base += 16) {
        int nch = deg - base; if (nch > 16) nch = 16;
        int s = 0; float e = 0.f;
        if (g16 < nch) {
            s = csr[beg + base + g16];
            e = __expf(leaky(a_s[s] + ad));
            sum += e;
        }
        int t = 0;
        for (; t + 4 <= nch; t += 4) {
            int sA = __shfl(s, t, 16),     sB = __shfl(s, t + 1, 16);
            int sC = __shfl(s, t + 2, 16), sD = __shfl(s, t + 3, 16);
            f16x8 hA = *(const f16x8*)(xb + (size_t)sA * 128);
            f16x8 hB = *(const f16x8*)(xb + (size_t)sB * 128);
            f16x8 hC = *(const f16x8*)(xb + (size_t)sC * 128);
            f16x8 hD = *(const f16x8*)(xb + (size_t)sD * 128);
            float wA = __shfl(e, t, 16),     wB = __shfl(e, t + 1, 16);
            float wC = __shfl(e, t + 2, 16), wD = __shfl(e, t + 3, 16);
            #pragma unroll
            for (int p = 0; p < 4; ++p) {
                f32x2 vA = { (float)hA[2*p], (float)hA[2*p+1] };
                f32x2 vB = { (float)hB[2*p], (float)hB[2*p+1] };
                f32x2 vC = { (float)hC[2*p], (float)hC[2*p+1] };
                f32x2 vD = { (float)hD[2*p], (float)hD[2*p+1] };
                acc[p] += wA * vA + wB * vB + wC * vC + wD * vD;
            }
        }
        for (; t < nch; ++t) {
            int   si = __shfl(s, t, 16);
            float w  = __shfl(e, t, 16);
            f16x8 hv = *(const f16x8*)(xb + (size_t)si * 128);
            #pragma unroll
            for (int p = 0; p < 4; ++p) {
                f32x2 v = { (float)hv[2*p], (float)hv[2*p+1] };
                acc[p] += w * v;
            }
        }
    }
    #pragma unroll
    for (int o = 1; o < 16; o <<= 1) sum += __shfl_xor(sum, o, 16);
    float inv = 1.f / (sum + 1e-16f);
    f16x8 ov;
    #pragma unroll
    for (int p = 0; p < 4; ++p) {
        ov[2 * p]     = (_Float16)elu(acc[p].x * inv + b2[g16 * 8 + 2 * p]);
        ov[2 * p + 1] = (_Float16)elu(acc[p].y * inv + b2[g16 * 8 + 2 * p + 1]);
    }
    *(f16x8*)(h2 + (size_t)d * 128 + g16 * 8) = ov;
}

// ============ pooling stage A: chunked partial sums (h2 fp16) ============
#define PCH 64
__global__ __launch_bounds__(128) void k_poolA(const _Float16* __restrict__ h2,
                                               const int* __restrict__ batch,
                                               float* __restrict__ pooled, int N)
{
    int c = threadIdx.x;
    int n0 = blockIdx.x * PCH;
    int n1 = n0 + PCH < N ? n0 + PCH : N;
    if (n0 >= N) return;
    int g = batch[n0];
    float acc = 0.f;
    for (int n = n0; n < n1; ++n) {
        int bg = batch[n];
        if (bg != g) { atomicAdd(&pooled[(size_t)g * 128 + c], acc); acc = 0.f; g = bg; }
        acc += (float)h2[(size_t)n * 128 + c];
    }
    atomicAdd(&pooled[(size_t)g * 128 + c], acc);
}

// ============ head: mean + relu(pooled@Wh1^T+bh1) @ Wh2^T + bh2 ============
__global__ __launch_bounds__(128) void k_head(const float* __restrict__ pooled,
                                              const int* __restrict__ gstart,
                                              const float* __restrict__ Wh1,
                                              const float* __restrict__ bh1,
                                              const float* __restrict__ Wh2,
                                              const float* __restrict__ bh2,
                                              float* __restrict__ out)
{
    int g = blockIdx.x, c = threadIdx.x;
    __shared__ float p[128];
    __shared__ float red[128];
    float cf = (float)(gstart[g + 1] - gstart[g]); cf = cf > 1.f ? cf : 1.f;
    p[c] = pooled[(size_t)g * 128 + c] / cf;
    __syncthreads();
    float z = bh1[c];
    for (int k = 0; k < 128; ++k) z += p[k] * Wh1[c * 128 + k];
    z = z > 0.f ? z : 0.f;
    red[c] = z * Wh2[c];
    __syncthreads();
    for (int st = 64; st > 0; st >>= 1) { if (c < st) red[c] += red[c + st]; __syncthreads(); }
    if (c == 0) out[g] = red[0] + bh2[0];
}

// ============ launch ============
extern "C" void kernel_launch(void* const* d_in, const int* in_sizes, int n_in,
                              void* d_out, int out_size, void* d_ws, size_t ws_size,
                              hipStream_t stream)
{
    const float* x   = (const float*)d_in[0];
    const int*   ei  = (const int*)d_in[1];
    const int*   bat = (const int*)d_in[2];
    const float* W1  = (const float*)d_in[3];
    const float* as1 = (const float*)d_in[4];
    const float* ad1 = (const float*)d_in[5];
    const float* b1  = (const float*)d_in[6];
    const float* W2  = (const float*)d_in[7];
    const float* as2 = (const float*)d_in[8];
    const float* ad2 = (const float*)d_in[9];
    const float* b2  = (const float*)d_in[10];
    const float* Wh1 = (const float*)d_in[11];
    const float* bh1 = (const float*)d_in[12];
    const float* Wh2 = (const float*)d_in[13];
    const float* bh2 = (const float*)d_in[14];
    float* out = (float*)d_out;

    const int N  = in_sizes[0] / 128;
    const int E  = in_sizes[1] / 2;
    const int Ep = E + N;
    const int G  = 128;

    char* w = (char*)d_ws;
    size_t off = 0;
    auto alloc = [&](size_t bytes) -> char* {
        char* p = w + off; off += (bytes + 511) & ~(size_t)511; return p;
    };
    _Float16* x_h  = (_Float16*)alloc((size_t)N * 128 * 2);
    _Float16* agg  = (_Float16*)alloc((size_t)N * 512 * 2);
    _Float16* h1   = (_Float16*)alloc((size_t)N * 512 * 2);
    _Float16* xh2h = (_Float16*)alloc((size_t)N * 128 * 2);
    _Float16* h2   = (_Float16*)alloc((size_t)N * 128 * 2);
    float*    As1  = (float*)alloc((size_t)N * 4 * 4);
    float*    Ad1  = (float*)alloc((size_t)N * 4 * 4);
    float*    As2  = (float*)alloc((size_t)N * 4);
    float*    Ad2  = (float*)alloc((size_t)N * 4);
    float*    w_s1 = (float*)alloc(512 * 4);
    float*    w_d1 = (float*)alloc(512 * 4);
    _Float16* W1hi = (_Float16*)alloc(65536 * 2);
    _Float16* W1lo = (_Float16*)alloc(65536 * 2);
    _Float16* W2hi = (_Float16*)alloc(65536 * 2);
    _Float16* W2lo = (_Float16*)alloc(65536 * 2);
    int* startb = (int*)alloc((size_t)(N + 1) * 4);
    unsigned short* csr  = (unsigned short*)alloc((size_t)Ep * 2);
    unsigned short* rank = (unsigned short*)alloc((size_t)Ep * 2);
    int* sums   = (int*)alloc(4096);
    int* gstart = (int*)alloc((size_t)(G + 1) * 4);
    char* zbase = w + off;                                // zero-init group
    int*   deg    = (int*)alloc((size_t)N * 4);
    float* pooled = (float*)alloc((size_t)G * 128 * 4);
    size_t zbytes = (size_t)((w + off) - zbase);

    hipMemsetAsync(zbase, 0, zbytes, stream);

    // 1) weights -> split fp16 + fold attention vectors (one kernel)
    k_prep<<<514, 256, 0, stream>>>(W1, W2, as1, ad1, W1hi, W1lo, W2hi, W2lo, w_s1, w_d1);
    // 2) layer-1 logits + fp16 x
    k_attn_x<<<(N + 3) / 4, 256, 0, stream>>>(x, w_s1, w_d1, As1, Ad1, x_h, N);
    // 3) CSR count+rank, fused graph boundaries
    int nbc = (Ep + 255) / 256, nbg = (N + 255) / 256;
    k_count<<<nbc + nbg, 256, 0, stream>>>(ei, deg, rank, bat, gstart, E, Ep, N, G, nbc);
    int nb = (N + 1 + 1023) / 1024;
    k_scanA<<<nb, 1024, 0, stream>>>(deg, startb, sums, N + 1, N);
    k_scanB<<<1, 64, 0, stream>>>(sums, nb);
    k_scanC<<<nb, 1024, 0, stream>>>(startb, sums, N + 1);
    k_fill<<<(Ep + 255) / 256, 256, 0, stream>>>(ei, startb, rank, csr, E, Ep);
    // 4) layer-1 gather -> agg fp16 [N, 4*128]
    k_gat1<<<(N + 15) / 16, 256, 0, stream>>>(startb, csr, As1, Ad1, x_h, agg, N);
    // 5) block-diag projection + bias + ELU (fp16 MFMA)
    k_gemm_h<true, false><<<dim3((N + 127) / 128, 1, 4), 256, 0, stream>>>(
        agg, W1hi, W1lo, b1, h1, nullptr, nullptr, nullptr, nullptr,
        N, 128, 512, 128, 512, 128L, 16384L, 128L, 128L);
    // 6) xh2 = h1 @ W2^T + fused layer-2 attn logits
    k_gemm_h<false, true><<<dim3((N + 127) / 128, 1, 1), 256, 0, stream>>>(
        h1, W2hi, W2lo, nullptr, xh2h, as2, ad2, As2, Ad2,
        N, 512, 512, 512, 128, 0L, 0L, 0L, 0L);
    // 7) layer-2 gather + bias + ELU -> h2 fp16
    k_gat2<<<(N + 15) / 16, 256, 0, stream>>>(startb, csr, As2, Ad2, xh2h, b2, h2, N);
    // 8) two-stage pooling + MLP head
    k_poolA<<<(N + PCH - 1) / PCH, 128, 0, stream>>>(h2, bat, pooled, N);
    k_head<<<G, 128, 0, stream>>>(pooled, gstart, Wh1, bh1, Wh2, bh2, out);
}